// Round 1
// baseline (77.650 us; speedup 1.0000x reference)
//
#include <hip/hip_runtime.h>

typedef _Float16 half8 __attribute__((ext_vector_type(8)));
typedef _Float16 half4v __attribute__((ext_vector_type(4)));
typedef float f32x16 __attribute__((ext_vector_type(16)));

// ---------------------------------------------------------------------------
// Pre-pack W [55,64,64] f32 -> f16 fragments for v_mfma_f32_32x32x16_f16.
// Bp[((l*4+chunk)*2+nt)*512 + lane*8 + v] = W[l, chunk*16+(lane>>5)*8+v, nt*32+(lane&31)]
// ---------------------------------------------------------------------------
__global__ __launch_bounds__(256)
void prepack_kernel(const float* __restrict__ W, _Float16* __restrict__ Bp) {
  const int idx = blockIdx.x * 256 + threadIdx.x;
  if (idx >= 55 * 4 * 2 * 64 * 8) return;
  const int v     = idx & 7;
  const int lam   = (idx >> 3) & 63;
  const int nt    = (idx >> 9) & 1;
  const int chunk = (idx >> 10) & 3;
  const int l     = idx >> 12;
  const int c = chunk * 16 + (lam >> 5) * 8 + v;
  const int o = nt * 32 + (lam & 31);
  Bp[idx] = (_Float16)W[(l * 64 + c) * 64 + o];
}

// ---------------------------------------------------------------------------
// Main kernel: block = 128 threads (2 waves), covers 2 image rows of one batch
// image. Wave w handles row h0+w: M=64 pixels as 2 m-tiles of 32, N=64 as
// 2 n-tiles of 32. K = 55 features x 64 ch, looped as chunk(16ch) x l(55).
// ---------------------------------------------------------------------------
__global__ __launch_bounds__(128, 2)
void qconv_kernel(const float* __restrict__ x, const _Float16* __restrict__ Bp,
                  float* __restrict__ out) {
  constexpr int IU[45] = {0,0,0,0,0,0,0,0,0, 1,1,1,1,1,1,1,1, 2,2,2,2,2,2,2,
                          3,3,3,3,3,3, 4,4,4,4,4, 5,5,5,5, 6,6,6, 7,7, 8};
  constexpr int JU[45] = {0,1,2,3,4,5,6,7,8, 1,2,3,4,5,6,7,8, 2,3,4,5,6,7,8,
                          3,4,5,6,7,8, 4,5,6,7,8, 5,6,7,8, 6,7,8, 7,8, 8};

  const int tid  = threadIdx.x;
  const int wave = tid >> 6;          // 0..1 -> image row h0+wave
  const int lane = tid & 63;
  const int blk  = blockIdx.x;        // 512 blocks
  const int b    = blk >> 5;          // batch image 0..15
  const int h0   = (blk & 31) * 2;    // first of 2 rows

  // x tile: 4 halo rows x 66 cols x 64 ch, f16, XOR-swizzled (ch stride 128B)
  __shared__ __align__(16) unsigned char xs[4 * 66 * 128];

  for (int idx = tid; idx < 4 * 66 * 16; idx += 128) {
    const int row = idx / (66 * 16);
    const int rem = idx - row * (66 * 16);
    const int col = rem >> 4;
    const int cg  = rem & 15;
    const int h = h0 - 1 + row;
    const int w = col - 1;
    float4 v = make_float4(0.f, 0.f, 0.f, 0.f);
    if ((unsigned)h < 64u && (unsigned)w < 64u)
      v = *(const float4*)(x + ((((size_t)b * 64 + h) * 64 + w) * 64 + cg * 4));
    half4v hv;
    hv[0] = (_Float16)v.x; hv[1] = (_Float16)v.y;
    hv[2] = (_Float16)v.z; hv[3] = (_Float16)v.w;
    const int addr = (row * 8448 + col * 128 + cg * 8) ^ ((col & 7) << 4);
    *(half4v*)(xs + addr) = hv;
  }
  __syncthreads();

  f32x16 acc00 = {}; f32x16 acc01 = {};
  f32x16 acc10 = {}; f32x16 acc11 = {};

  const int colA = lane & 31;   // pixel col within m-tile (A-frag row)
  const int kg   = lane >> 5;   // k-half
  const half8 ones = {(_Float16)1, (_Float16)1, (_Float16)1, (_Float16)1,
                      (_Float16)1, (_Float16)1, (_Float16)1, (_Float16)1};

  for (int chunk = 0; chunk < 4; ++chunk) {
    const int cbyte = chunk * 32 + kg * 16;   // byte offset of lane's 8 ch

    // load the 9 taps for both m-tiles into registers (this chunk's 8 ch/lane)
    half8 tap0[9], tap1[9];
#pragma unroll
    for (int t = 0; t < 9; ++t) {
      const int r = wave + t / 3;             // LDS row 0..3
      int ce = colA + (t % 3);                // swizzled col (mt0)
      const int a0 = (r * 8448 + ce * 128 + cbyte) ^ ((ce & 7) << 4);
      tap0[t] = *(const half8*)(xs + a0);
      ce += 32;                               // mt1
      const int a1 = (r * 8448 + ce * 128 + cbyte) ^ ((ce & 7) << 4);
      tap1[t] = *(const half8*)(xs + a1);
    }

    // B fragment stream from L2 (pre-packed, 16B/lane coalesced)
    const _Float16* Bc = Bp + (size_t)chunk * 1024 + lane * 8;  // + l*4096 + nt*512
    half8 bpref[2][2];
    bpref[0][0] = *(const half8*)(Bc + 0);
    bpref[0][1] = *(const half8*)(Bc + 512);
    bpref[1][0] = *(const half8*)(Bc + 4096);
    bpref[1][1] = *(const half8*)(Bc + 4096 + 512);

#pragma unroll
    for (int l = 0; l < 55; ++l) {
      const half8 bf0 = bpref[l & 1][0];
      const half8 bf1 = bpref[l & 1][1];
      if (l + 2 < 55) {   // constant after unroll
        bpref[l & 1][0] = *(const half8*)(Bc + (size_t)(l + 2) * 4096);
        bpref[l & 1][1] = *(const half8*)(Bc + (size_t)(l + 2) * 4096 + 512);
      }
      half8 a0, a1;
      if (l < 45) {
        a0 = tap0[IU[l]] * tap0[JU[l]];       // v_pk_mul_f16 x4
        a1 = tap1[IU[l]] * tap1[JU[l]];
      } else if (l < 54) {
        a0 = tap0[l - 45];
        a1 = tap1[l - 45];
      } else {
        a0 = ones; a1 = ones;
      }
      acc00 = __builtin_amdgcn_mfma_f32_32x32x16_f16(a0, bf0, acc00, 0, 0, 0);
      acc01 = __builtin_amdgcn_mfma_f32_32x32x16_f16(a0, bf1, acc01, 0, 0, 0);
      acc10 = __builtin_amdgcn_mfma_f32_32x32x16_f16(a1, bf0, acc10, 0, 0, 0);
      acc11 = __builtin_amdgcn_mfma_f32_32x32x16_f16(a1, bf1, acc11, 0, 0, 0);
    }
  }

  // epilogue: D layout col=lane&31, row=(g&3)+8*(g>>2)+4*(lane>>5)
  const int oL = lane & 31;
  const int rg = lane >> 5;
  float* op = out + (((size_t)b * 4096 + (size_t)(h0 + wave) * 64) * 64);
#pragma unroll
  for (int g = 0; g < 16; ++g) {
    const int rowD = (g & 3) + 8 * (g >> 2) + 4 * rg;
    op[(size_t)rowD * 64 + oL]             = acc00[g];
    op[(size_t)rowD * 64 + 32 + oL]        = acc01[g];
    op[(size_t)(32 + rowD) * 64 + oL]      = acc10[g];
    op[(size_t)(32 + rowD) * 64 + 32 + oL] = acc11[g];
  }
}

extern "C" void kernel_launch(void* const* d_in, const int* in_sizes, int n_in,
                              void* d_out, int out_size, void* d_ws, size_t ws_size,
                              hipStream_t stream) {
  const float* x = (const float*)d_in[0];
  const float* W = (const float*)d_in[1];
  float* out     = (float*)d_out;
  _Float16* Bp   = (_Float16*)d_ws;   // 450,560 bytes

  prepack_kernel<<<dim3((225280 + 255) / 256), dim3(256), 0, stream>>>(W, Bp);
  qconv_kernel<<<dim3(512), dim3(128), 0, stream>>>(x, Bp, out);
}

// Round 2
// 53.978 us; speedup vs baseline: 1.4386x; 1.4386x over previous
//
#include <hip/hip_runtime.h>

typedef _Float16 half8 __attribute__((ext_vector_type(8)));
typedef _Float16 half4v __attribute__((ext_vector_type(4)));
typedef float f32x16 __attribute__((ext_vector_type(16)));

// ---------------------------------------------------------------------------
// Pre-pack W [55,64,64] f32 -> f16 fragments for v_mfma_f32_32x32x16_f16,
// for l = 0..53 (quadratic + linear). l = 54 (bias, pixel-independent) is
// folded into bias[o] = sum_c W[54,c,o], appended as f32[64] after the frags.
// Bp[((l*4+chunk)*2+nt)*512 + lane*8 + v] =
//     W[l, chunk*16+(lane>>5)*8+v, nt*32+(lane&31)]
// ---------------------------------------------------------------------------
__global__ __launch_bounds__(256)
void prepack_kernel(const float* __restrict__ W, _Float16* __restrict__ Bp) {
  const int idx = blockIdx.x * 256 + threadIdx.x;
  if (idx < 221184) {                     // 54*4*2*512
    const int v     = idx & 7;
    const int lam   = (idx >> 3) & 63;
    const int nt    = (idx >> 9) & 1;
    const int chunk = (idx >> 10) & 3;
    const int l     = idx >> 12;
    const int c = chunk * 16 + (lam >> 5) * 8 + v;
    const int o = nt * 32 + (lam & 31);
    Bp[idx] = (_Float16)W[(l * 64 + c) * 64 + o];
  } else if (idx < 221184 + 64) {
    const int o = idx - 221184;
    float s = 0.f;
    for (int c = 0; c < 64; ++c) s += W[(54 * 64 + c) * 64 + o];
    ((float*)(Bp + 221184))[o] = s;
  }
}

// ---------------------------------------------------------------------------
// Main kernel: block = 256 threads (4 waves) = ONE image row (64 pixels).
// Wave w: nt = w&1 (output-channel half, N=32), ks = w>>1 (input-channel
// half: chunks {2ks, 2ks+1}). Each wave: M=64 (2 m-tiles of 32), N=32,
// K = 32 ch x 54 features. K-split partials reduced via LDS (overlaying the
// dead x-tile), bias added in the epilogue by the ks=0 waves.
// ---------------------------------------------------------------------------
__global__ __launch_bounds__(256, 4)
void qconv_kernel(const float* __restrict__ x, const _Float16* __restrict__ Bp,
                  float* __restrict__ out) {
  constexpr int IU[45] = {0,0,0,0,0,0,0,0,0, 1,1,1,1,1,1,1,1, 2,2,2,2,2,2,2,
                          3,3,3,3,3,3, 4,4,4,4,4, 5,5,5,5, 6,6,6, 7,7, 8};
  constexpr int JU[45] = {0,1,2,3,4,5,6,7,8, 1,2,3,4,5,6,7,8, 2,3,4,5,6,7,8,
                          3,4,5,6,7,8, 4,5,6,7,8, 5,6,7,8, 6,7,8, 7,8, 8};

  const int tid  = threadIdx.x;
  const int wave = tid >> 6;
  const int lane = tid & 63;
  const int nt   = wave & 1;
  const int ks   = wave >> 1;
  const int b    = blockIdx.x >> 6;
  const int h    = blockIdx.x & 63;

  // x tile: 3 halo rows x 66 cols x 64 ch, f16, XOR-swizzled (ch stride 128B).
  // 25,344 B; the 16 KB K-split reduction buffer overlays it after the main
  // loop (single __shared__ block, barrier-separated phases).
  __shared__ __align__(16) unsigned char smem[3 * 66 * 128];

  for (int idx = tid; idx < 3 * 66 * 16; idx += 256) {
    const int row = idx / (66 * 16);
    const int rem = idx - row * (66 * 16);
    const int col = rem >> 4;
    const int cg  = rem & 15;
    const int hs = h - 1 + row;
    const int w  = col - 1;
    float4 v = make_float4(0.f, 0.f, 0.f, 0.f);
    if ((unsigned)hs < 64u && (unsigned)w < 64u)
      v = *(const float4*)(x + ((((size_t)b * 64 + hs) * 64 + w) * 64 + cg * 4));
    half4v hv;
    hv[0] = (_Float16)v.x; hv[1] = (_Float16)v.y;
    hv[2] = (_Float16)v.z; hv[3] = (_Float16)v.w;
    const int addr = (row * 8448 + col * 128 + cg * 8) ^ ((col & 7) << 4);
    *(half4v*)(smem + addr) = hv;
  }
  __syncthreads();

  f32x16 acc0 = {};   // m-tile 0 (pixels 0..31),  n-cols nt*32..nt*32+31
  f32x16 acc1 = {};   // m-tile 1 (pixels 32..63)
  const int colA = lane & 31;
  const int kg   = lane >> 5;

  for (int chunk = 0; chunk < 2; ++chunk) {
    const int cc    = ks * 2 + chunk;          // actual 16-ch chunk 0..3
    const int cbyte = cc * 32 + kg * 16;

    half8 tap0[9], tap1[9];
#pragma unroll
    for (int t = 0; t < 9; ++t) {
      const int r = t / 3;
      int ce = colA + (t % 3);
      const int a0 = (r * 8448 + ce * 128 + cbyte) ^ ((ce & 7) << 4);
      tap0[t] = *(const half8*)(smem + a0);
      ce += 32;
      const int a1 = (r * 8448 + ce * 128 + cbyte) ^ ((ce & 7) << 4);
      tap1[t] = *(const half8*)(smem + a1);
    }

    // B fragments from L2 (pre-packed): one 16B load per l, depth-2 prefetch.
    const _Float16* Bc = Bp + (size_t)(cc * 2 + nt) * 512 + lane * 8;
    half8 bpref[2];
    bpref[0] = *(const half8*)(Bc);
    bpref[1] = *(const half8*)(Bc + 4096);
#pragma unroll
    for (int l = 0; l < 54; ++l) {
      const half8 bf = bpref[l & 1];
      if (l + 2 < 54)    // compile-time after unroll
        bpref[l & 1] = *(const half8*)(Bc + (size_t)(l + 2) * 4096);
      half8 a0, a1;
      if (l < 45) {
        a0 = tap0[IU[l]] * tap0[JU[l]];        // v_pk_mul_f16 x4
        a1 = tap1[IU[l]] * tap1[JU[l]];
      } else {
        a0 = tap0[l - 45];
        a1 = tap1[l - 45];
      }
      acc0 = __builtin_amdgcn_mfma_f32_32x32x16_f16(a0, bf, acc0, 0, 0, 0);
      acc1 = __builtin_amdgcn_mfma_f32_32x32x16_f16(a1, bf, acc1, 0, 0, 0);
    }
  }

  // ---- K-split reduction: ks=1 waves park partials in LDS (x-tile is dead),
  // ks=0 waves add, apply bias, and store.
  __syncthreads();
  float* red = (float*)smem;                   // [nt][64 pix][32 col] f32
  const int col = lane & 31;
  const int rg  = lane >> 5;

  if (ks == 1) {
#pragma unroll
    for (int g = 0; g < 16; ++g) {
      const int rowD = (g & 3) + 8 * (g >> 2) + 4 * rg;
      red[(nt * 64 + rowD) * 32 + col]      = acc0[g];
      red[(nt * 64 + 32 + rowD) * 32 + col] = acc1[g];
    }
  }
  __syncthreads();
  if (ks == 0) {
    const float bias = ((const float*)(Bp + 221184))[nt * 32 + col];
    float* op = out + ((size_t)b * 64 + h) * 4096 + nt * 32 + col;
#pragma unroll
    for (int g = 0; g < 16; ++g) {
      const int rowD = (g & 3) + 8 * (g >> 2) + 4 * rg;
      op[(size_t)rowD * 64] =
          acc0[g] + red[(nt * 64 + rowD) * 32 + col] + bias;
      op[(size_t)(32 + rowD) * 64] =
          acc1[g] + red[(nt * 64 + 32 + rowD) * 32 + col] + bias;
    }
  }
}

extern "C" void kernel_launch(void* const* d_in, const int* in_sizes, int n_in,
                              void* d_out, int out_size, void* d_ws, size_t ws_size,
                              hipStream_t stream) {
  const float* x = (const float*)d_in[0];
  const float* W = (const float*)d_in[1];
  float* out     = (float*)d_out;
  _Float16* Bp   = (_Float16*)d_ws;   // 442,368 B frags + 256 B bias

  prepack_kernel<<<dim3((221248 + 255) / 256), dim3(256), 0, stream>>>(W, Bp);
  qconv_kernel<<<dim3(1024), dim3(256), 0, stream>>>(x, Bp, out);
}

// Round 3
// 49.629 us; speedup vs baseline: 1.5646x; 1.0876x over previous
//
#include <hip/hip_runtime.h>

typedef _Float16 half8 __attribute__((ext_vector_type(8)));
typedef _Float16 half4v __attribute__((ext_vector_type(4)));
typedef float f32x16 __attribute__((ext_vector_type(16)));

#define RING_OFF 33792          // x-tile: 4*66*128 = 33792 B
#define LDS_TOTAL (33792 + 16384)

// async global->LDS, 4 B per lane (dest = wave-uniform base + lane*4)
__device__ __forceinline__ void stage4(const void* g, void* l) {
  __builtin_amdgcn_global_load_lds(
      (const __attribute__((address_space(1))) unsigned int*)(unsigned long long)g,
      (__attribute__((address_space(3))) unsigned int*)(unsigned int)(unsigned long long)l,
      4, 0, 0);
}

// ---------------------------------------------------------------------------
// Pre-pack W [55,64,64] f32 -> f16 MFMA B-fragments, frag order [cp][l][ks][nt]
// (cp = chunk parity, cc = 2*ks+cp). Bias row (l=54) folded to f32[64] at end.
// frag f = ((cp*54 + l)*2 + ks)*2 + nt; elem = lane*8+v;
// value = W[l, cc*16 + (lane>>5)*8 + v, nt*32 + (lane&31)]
// ---------------------------------------------------------------------------
__global__ __launch_bounds__(256)
void prepack_kernel(const float* __restrict__ W, _Float16* __restrict__ Bp) {
  const int idx = blockIdx.x * 256 + threadIdx.x;
  if (idx < 221184) {                    // 432 frags * 512 elems
    const int v   = idx & 7;
    const int lam = (idx >> 3) & 63;
    const int f   = idx >> 9;
    const int nt  = f & 1;
    const int ks  = (f >> 1) & 1;
    const int lf  = (f >> 2) % 54;
    const int cp  = (f >> 2) / 54;
    const int cc  = ks * 2 + cp;
    const int c   = cc * 16 + (lam >> 5) * 8 + v;
    const int o   = nt * 32 + (lam & 31);
    Bp[idx] = (_Float16)W[(lf * 64 + c) * 64 + o];
  } else if (idx < 221184 + 64) {
    const int o = idx - 221184;
    float s = 0.f;
    for (int c = 0; c < 64; ++c) s += W[(54 * 64 + c) * 64 + o];
    ((float*)(Bp + 221184))[o] = s;
  }
}

// ---------------------------------------------------------------------------
// Block = 1024 thr = 16 waves = 2 image rows. Wave = (mh 0..3, nt 0..1, ks 0..1):
// mh -> (row mh>>1, pixel-half mh&1), M=32, N=32, K = 2 chunks x 54 l.
// B frags staged async into a 2x8KB LDS ring, 2 super-phases ahead, vmcnt(2).
// Each frag shared by the 4 mh-waves. K-split (ks) reduced via LDS at the end.
// ---------------------------------------------------------------------------
__global__ __launch_bounds__(1024, 4)
void qconv_kernel(const float* __restrict__ x, const _Float16* __restrict__ Bp,
                  float* __restrict__ out) {
  constexpr int IU[45] = {0,0,0,0,0,0,0,0,0, 1,1,1,1,1,1,1,1, 2,2,2,2,2,2,2,
                          3,3,3,3,3,3, 4,4,4,4,4, 5,5,5,5, 6,6,6, 7,7, 8};
  constexpr int JU[45] = {0,1,2,3,4,5,6,7,8, 1,2,3,4,5,6,7,8, 2,3,4,5,6,7,8,
                          3,4,5,6,7,8, 4,5,6,7,8, 5,6,7,8, 6,7,8, 7,8, 8};

  const int tid  = threadIdx.x;
  const int wave = tid >> 6;
  const int lane = tid & 63;
  const int mh   = wave & 3;
  const int nt   = (wave >> 2) & 1;
  const int ks   = wave >> 3;
  const int b    = blockIdx.x >> 5;
  const int h0   = (blockIdx.x & 31) * 2;

  __shared__ __align__(16) unsigned char smem[LDS_TOTAL];

  // ---- x tile: rows h0-1..h0+2 (4) x 66 cols x 64 ch, f16, XOR-swizzled
  for (int idx = tid; idx < 4 * 66 * 16; idx += 1024) {
    const int row = idx / (66 * 16);
    const int rem = idx - row * (66 * 16);
    const int col = rem >> 4;
    const int cg  = rem & 15;
    const int hs  = h0 - 1 + row;
    const int w   = col - 1;
    float4 v = make_float4(0.f, 0.f, 0.f, 0.f);
    if ((unsigned)hs < 64u && (unsigned)w < 64u)
      v = *(const float4*)(x + ((((size_t)b * 64 + hs) * 64 + w) * 64 + cg * 4));
    half4v hv;
    hv[0] = (_Float16)v.x; hv[1] = (_Float16)v.y;
    hv[2] = (_Float16)v.z; hv[3] = (_Float16)v.w;
    const int addr = (row * 8448 + col * 128 + cg * 8) ^ ((col & 7) << 4);
    *(half4v*)(smem + addr) = hv;
  }
  __syncthreads();

  const char* BpB = (const char*)Bp;
  const int wbase = wave * 256;     // wave-uniform dest slice within each 4KB

#define STAGE(SPG) do {                                                  \
    const char* s_ = BpB + (SPG) * 8192 + tid * 4;                       \
    char* d_ = (char*)smem + RING_OFF + ((SPG) & 1) * 8192 + wbase;      \
    stage4(s_, d_); stage4(s_ + 4096, d_ + 4096);                        \
  } while (0)

  STAGE(0); STAGE(1);               // prologue: 2 super-phases in flight

  f32x16 acc = {};
  const int colA = lane & 31;
  const int kg   = lane >> 5;
  const int r0   = mh >> 1;
  const int wseg = mh & 1;
  const unsigned fbase = RING_OFF + (ks * 2 + nt) * 1024 + lane * 16;

#pragma unroll
  for (int cp = 0; cp < 2; ++cp) {
    const int cc    = ks * 2 + cp;
    const int cbyte = cc * 32 + kg * 16;

    half8 tap[9];
#pragma unroll
    for (int t = 0; t < 9; ++t) {
      const int ce = wseg * 32 + colA + (t % 3);
      const int a  = ((r0 + t / 3) * 8448 + ce * 128 + cbyte) ^ ((ce & 7) << 4);
      tap[t] = *(const half8*)(smem + a);
    }

#pragma unroll
    for (int s = 0; s < 27; ++s) {
      const int spg = cp * 27 + s;
      // wait for THIS super-phase's staged 8KB (2 insts/thread in flight per sp)
      if (spg < 53) { asm volatile("s_waitcnt vmcnt(2)" ::: "memory"); }
      else          { asm volatile("s_waitcnt vmcnt(0)" ::: "memory"); }
      __builtin_amdgcn_s_barrier();
#pragma unroll
      for (int j = 0; j < 2; ++j) {
        const int l = s * 2 + j;
        const half8 bf =
            *(const half8*)(smem + (spg & 1) * 8192 + j * 4096 + fbase);
        half8 a;
        if (l < 45) a = tap[IU[l]] * tap[JU[l]];   // v_pk_mul_f16 x4
        else        a = tap[l - 45];
        acc = __builtin_amdgcn_mfma_f32_32x32x16_f16(a, bf, acc, 0, 0, 0);
      }
      // my reads of this ring buffer are retired -> safe for others to overwrite
      asm volatile("s_waitcnt lgkmcnt(0)" ::: "memory");
      __builtin_amdgcn_s_barrier();
      if (spg < 52) STAGE(spg + 2);
    }
  }
#undef STAGE

  // ---- ks-split reduction (red overlays x-tile + ring, both dead) ----
  __syncthreads();
  float* red = (float*)smem;        // [mh][nt][32 rows][32 cols] f32 = 32KB
  const int colD = lane & 31;
  const int rg   = lane >> 5;

  if (ks == 1) {
#pragma unroll
    for (int g = 0; g < 16; ++g) {
      const int rowD = (g & 3) + 8 * (g >> 2) + 4 * rg;
      red[(mh * 2 + nt) * 1024 + rowD * 32 + colD] = acc[g];
    }
  }
  __syncthreads();
  if (ks == 0) {
    const float bias = ((const float*)(Bp + 221184))[nt * 32 + colD];
    float* op = out + (((size_t)b * 64 + h0 + r0) * 64 + wseg * 32) * 64
                    + nt * 32 + colD;
#pragma unroll
    for (int g = 0; g < 16; ++g) {
      const int rowD = (g & 3) + 8 * (g >> 2) + 4 * rg;
      op[(size_t)rowD * 64] =
          acc[g] + red[(mh * 2 + nt) * 1024 + rowD * 32 + colD] + bias;
    }
  }
}

extern "C" void kernel_launch(void* const* d_in, const int* in_sizes, int n_in,
                              void* d_out, int out_size, void* d_ws, size_t ws_size,
                              hipStream_t stream) {
  const float* x = (const float*)d_in[0];
  const float* W = (const float*)d_in[1];
  float* out     = (float*)d_out;
  _Float16* Bp   = (_Float16*)d_ws;   // 442,368 B frags + 256 B bias

  prepack_kernel<<<dim3((221248 + 255) / 256), dim3(256), 0, stream>>>(W, Bp);
  qconv_kernel<<<dim3(512), dim3(1024), 0, stream>>>(x, Bp, out);
}